// Round 1
// baseline (958.768 us; speedup 1.0000x reference)
//
#include <hip/hip_runtime.h>
#include <hip/hip_bf16.h>

#define BB 2
#define SS 2048
#define DD 4096
#define HH 32
#define KVH 8
#define HDD 128

using bf16 = __hip_bfloat16;
typedef __attribute__((ext_vector_type(8))) __bf16 bf16x8;
typedef __attribute__((ext_vector_type(4))) float f32x4;

#define GLOAD16(gp, lp) __builtin_amdgcn_global_load_lds(                     \
    (const __attribute__((address_space(1))) void*)(gp),                      \
    (__attribute__((address_space(3))) void*)(lp), 16, 0, 0)

// ---------------- fp32 -> bf16 cast (vectorized) ----------------
__global__ __launch_bounds__(256) void cast_kernel(
    const float* __restrict__ s, bf16* __restrict__ d, int n4) {
  int i = blockIdx.x * blockDim.x + threadIdx.x;
  if (i >= n4) return;
  float4 v = ((const float4*)s)[i];
  bf16 a0 = __float2bfloat16(v.x), a1 = __float2bfloat16(v.y);
  bf16 a2 = __float2bfloat16(v.z), a3 = __float2bfloat16(v.w);
  ushort4 u;
  u.x = reinterpret_cast<unsigned short&>(a0);
  u.y = reinterpret_cast<unsigned short&>(a1);
  u.z = reinterpret_cast<unsigned short&>(a2);
  u.w = reinterpret_cast<unsigned short&>(a3);
  ((ushort4*)d)[i] = u;
}

// ---------------- RoPE in place on q (B,S,H,HD) and k (B,S,KV,HD) ----------
__global__ __launch_bounds__(256) void rope_kernel(
    bf16* __restrict__ qb, bf16* __restrict__ kb,
    const float* __restrict__ fc, const float* __restrict__ fs) {
  int idx = blockIdx.x * blockDim.x + threadIdx.x;
  const int QP = BB * SS * HH * (HDD / 2);   // 8388608 q pairs
  const int KP = BB * SS * KVH * (HDD / 2);  // 2097152 k pairs
  bf16* p;
  int s, i;
  if (idx < QP) {
    int hr = idx >> 6;                 // (b*S+s)*H + h
    s = (hr >> 5) & (SS - 1);
    i = idx & 63;
    p = qb + ((size_t)hr << 7) + (i << 1);
  } else {
    int j = idx - QP;
    if (j >= KP) return;
    int hr = j >> 6;                   // (b*S+s)*KV + kv
    s = (hr >> 3) & (SS - 1);
    i = j & 63;
    p = kb + ((size_t)hr << 7) + (i << 1);
  }
  float c = fc[s * 64 + i], sn = fs[s * 64 + i];
  float x0 = __bfloat162float(p[0]), x1 = __bfloat162float(p[1]);
  p[0] = __float2bfloat16(x0 * c - x1 * sn);
  p[1] = __float2bfloat16(x0 * sn + x1 * c);
}

// ---------------- GEMM: C[M,N] = A[M,K] @ B[N,K]^T  (bf16 in, fp32 acc) ----
// MODE 0: bf16 row-major C; MODE 1: fp32 row-major C;
// MODE 2: bf16 store transposed-V layout vt[((b*KV+kv)*HD+d)*S + s]
template <int MODE>
__global__ __launch_bounds__(256, 2) void gemm_bt(
    const bf16* __restrict__ A, const bf16* __restrict__ Bm,
    void* __restrict__ C, int M, int N, int K) {
  __shared__ __attribute__((aligned(16))) bf16 As[128 * 64];  // 16 KB
  __shared__ __attribute__((aligned(16))) bf16 Bs[128 * 64];  // 16 KB
  const int m0 = blockIdx.y * 128, n0 = blockIdx.x * 128;
  const int t = threadIdx.x;
  const int lane = t & 63, w = t >> 6;
  const int wm = (w >> 1) * 64, wn = (w & 1) * 64;
  const int lr = lane & 15, quad = lane >> 4;

  // staging: tile rows 64B -> 8 chunks of 16B; XOR-swizzle chunk slot by row
  const int srow = t >> 3;                               // 0..31 (+32i)
  const int scol8 = ((t & 7) ^ (srow & 7)) * 8;          // i*32 doesn't change row&7
  const bf16* aSrc = A + (size_t)(m0 + srow) * K + scol8;
  const bf16* bSrc = Bm + (size_t)(n0 + srow) * K + scol8;
  bf16* aDst = As + t * 8;
  bf16* bDst = Bs + t * 8;

  // fragment read slots (swizzled), kk = 0/1
  const int sl[2] = {((0 * 4 + quad) ^ (lr & 7)) * 8, ((1 * 4 + quad) ^ (lr & 7)) * 8};

  f32x4 acc[4][4];
#pragma unroll
  for (int i = 0; i < 4; i++)
#pragma unroll
    for (int j = 0; j < 4; j++) acc[i][j] = (f32x4)0.0f;

  for (int k0 = 0; k0 < K; k0 += 64) {
#pragma unroll
    for (int i = 0; i < 4; i++) {
      GLOAD16(aSrc + i * 32 * K, aDst + i * 2048);
      GLOAD16(bSrc + i * 32 * K, bDst + i * 2048);
    }
    __syncthreads();
#pragma unroll
    for (int kk = 0; kk < 2; kk++) {
      bf16x8 af[4], bfv[4];
#pragma unroll
      for (int i = 0; i < 4; i++)
        af[i] = *(const bf16x8*)(As + (wm + i * 16 + lr) * 64 + sl[kk]);
#pragma unroll
      for (int j = 0; j < 4; j++)
        bfv[j] = *(const bf16x8*)(Bs + (wn + j * 16 + lr) * 64 + sl[kk]);
#pragma unroll
      for (int i = 0; i < 4; i++)
#pragma unroll
        for (int j = 0; j < 4; j++)
          acc[i][j] = __builtin_amdgcn_mfma_f32_16x16x32_bf16(af[i], bfv[j], acc[i][j], 0, 0, 0);
    }
    __syncthreads();
    aSrc += 64;
    bSrc += 64;
  }

  // epilogue: C/D layout col=lane&15, row=quad*4+reg
#pragma unroll
  for (int i = 0; i < 4; i++)
#pragma unroll
    for (int j = 0; j < 4; j++)
#pragma unroll
      for (int r = 0; r < 4; r++) {
        int row = m0 + wm + i * 16 + quad * 4 + r;
        int col = n0 + wn + j * 16 + lr;
        float v = acc[i][j][r];
        if (MODE == 0) {
          ((bf16*)C)[(size_t)row * N + col] = __float2bfloat16(v);
        } else if (MODE == 1) {
          ((float*)C)[(size_t)row * N + col] = v;
        } else {
          int bb = row >> 11, s = row & (SS - 1);
          int kv = col >> 7, d = col & (HDD - 1);
          ((bf16*)C)[((size_t)(bb * KVH + kv) * HDD + d) * SS + s] = __float2bfloat16(v);
        }
      }
}

// ---------------- causal flash attention, GQA (4 q-heads per kv-head) ------
// q: (B,S,H,HD) bf16 (RoPE'd); k: (B,S,KV,HD) bf16 (RoPE'd);
// vt: (B,KV,HD,S) bf16 (pre-transposed); out: (B,S,H*HD) bf16
__global__ __launch_bounds__(256, 2) void flash_kernel(
    const bf16* __restrict__ q, const bf16* __restrict__ k,
    const bf16* __restrict__ vt, bf16* __restrict__ out) {
  __shared__ __attribute__((aligned(16))) bf16 Ks[64 * 128];  // 16 KB [key][d]
  __shared__ __attribute__((aligned(16))) bf16 Vs[128 * 64];  // 16 KB [d][key]
  __shared__ __attribute__((aligned(16))) bf16 Ps[64 * 72];   // 9 KB, stride 72
  const int qt = blockIdx.x, h = blockIdx.y, b = blockIdx.z;
  const int kv = h >> 2;
  const int t = threadIdx.x;
  const int lane = t & 63, w = t >> 6;
  const int lr = lane & 15, quad = lane >> 4;
  const int q0 = qt * 64;

  // Q fragments: rows w*16+lr, k-chunks c*32 + quad*8 (A-layout)
  bf16x8 qf[4];
  {
    const bf16* qp = q + ((size_t)(b * SS + q0 + w * 16 + lr) * HH + h) * HDD + quad * 8;
#pragma unroll
    for (int c = 0; c < 4; c++) qf[c] = *(const bf16x8*)(qp + c * 32);
  }

  f32x4 oa[8];
#pragma unroll
  for (int i = 0; i < 8; i++) oa[i] = (f32x4)0.0f;
  float m_i[4] = {-1e30f, -1e30f, -1e30f, -1e30f};
  float l_i[4] = {0.f, 0.f, 0.f, 0.f};
  const float scale = 0.08838834764831845f;  // 1/sqrt(128)

  // staging bases (XOR-swizzled source chunks; dest is forced lane-sequential)
  const int krow = t >> 4;                              // 0..15 (+16i)
  const int kcol8 = ((t & 15) ^ (krow & 15)) * 8;
  const bf16* kSrc0 = k + ((size_t)(b * SS + krow) * KVH + kv) * HDD + kcol8;
  const int vrow = t >> 3;                              // 0..31 (+32i)
  const int vcol8 = ((t & 7) ^ (vrow & 7)) * 8;
  const bf16* vSrc0 = vt + ((size_t)(b * KVH + kv) * HDD + vrow) * SS + vcol8;
  bf16* kDst = Ks + t * 8;
  bf16* vDst = Vs + t * 8;

  const int slV[2] = {((0 * 4 + quad) ^ (lr & 7)) * 8, ((1 * 4 + quad) ^ (lr & 7)) * 8};

  for (int kt = 0; kt <= qt; kt++) {
    const int kt0 = kt * 64;
    const bf16* kSrc = kSrc0 + (size_t)kt0 * (KVH * HDD);
    const bf16* vSrc = vSrc0 + kt0;
#pragma unroll
    for (int i = 0; i < 4; i++) {
      GLOAD16(kSrc + i * 16 * KVH * HDD, kDst + i * 2048);
      GLOAD16(vSrc + i * 32 * SS, vDst + i * 2048);
    }
    __syncthreads();

    // S = Q K^T : wave w computes rows [w*16, w*16+16) x all 64 keys
    f32x4 sc4[4];
#pragma unroll
    for (int ni = 0; ni < 4; ni++) sc4[ni] = (f32x4)0.0f;
#pragma unroll
    for (int c = 0; c < 4; c++) {
#pragma unroll
      for (int ni = 0; ni < 4; ni++) {
        int row = ni * 16 + lr;  // key index in tile; row&15 == lr
        bf16x8 kf = *(const bf16x8*)(Ks + row * 128 + (((c * 4 + quad) ^ lr) * 8));
        sc4[ni] = __builtin_amdgcn_mfma_f32_16x16x32_bf16(qf[c], kf, sc4[ni], 0, 0, 0);
      }
    }

    // scale + causal mask + row max
    float mx[4] = {-1e30f, -1e30f, -1e30f, -1e30f};
#pragma unroll
    for (int ni = 0; ni < 4; ni++)
#pragma unroll
      for (int r = 0; r < 4; r++) {
        float v = sc4[ni][r] * scale;
        int kidx = kt0 + ni * 16 + lr;
        int qidx = q0 + w * 16 + quad * 4 + r;
        v = (kidx > qidx) ? -1e30f : v;
        sc4[ni][r] = v;
        mx[r] = fmaxf(mx[r], v);
      }
#pragma unroll
    for (int off = 1; off < 16; off <<= 1)
#pragma unroll
      for (int r = 0; r < 4; r++) mx[r] = fmaxf(mx[r], __shfl_xor(mx[r], off));

    float alpha[4], rs[4];
#pragma unroll
    for (int r = 0; r < 4; r++) {
      float mn = fmaxf(m_i[r], mx[r]);
      alpha[r] = __expf(m_i[r] - mn);
      m_i[r] = mn;
      rs[r] = 0.f;
    }
#pragma unroll
    for (int ni = 0; ni < 4; ni++)
#pragma unroll
      for (int r = 0; r < 4; r++) {
        float p = __expf(sc4[ni][r] - m_i[r]);
        sc4[ni][r] = p;
        rs[r] += p;
      }
#pragma unroll
    for (int off = 1; off < 16; off <<= 1)
#pragma unroll
      for (int r = 0; r < 4; r++) rs[r] += __shfl_xor(rs[r], off);
#pragma unroll
    for (int r = 0; r < 4; r++) l_i[r] = l_i[r] * alpha[r] + rs[r];
#pragma unroll
    for (int ni = 0; ni < 8; ni++)
#pragma unroll
      for (int r = 0; r < 4; r++) oa[ni][r] *= alpha[r];

    // P: C-layout -> LDS (per-wave strip, stride 72 keeps 16B align, breaks conflicts)
#pragma unroll
    for (int ni = 0; ni < 4; ni++)
#pragma unroll
      for (int r = 0; r < 4; r++)
        Ps[(w * 16 + quad * 4 + r) * 72 + ni * 16 + lr] = __float2bfloat16(sc4[ni][r]);

    // O += P @ V : A = P (A-layout, own strip), B = V^T rows (key-contiguous)
#pragma unroll
    for (int kk = 0; kk < 2; kk++) {
      bf16x8 pf = *(const bf16x8*)(Ps + (w * 16 + lr) * 72 + kk * 32 + quad * 8);
#pragma unroll
      for (int ni = 0; ni < 8; ni++) {
        bf16x8 vf = *(const bf16x8*)(Vs + (ni * 16 + lr) * 64 + slV[kk]);
        oa[ni] = __builtin_amdgcn_mfma_f32_16x16x32_bf16(pf, vf, oa[ni], 0, 0, 0);
      }
    }
    __syncthreads();
  }

  // epilogue: O / l, write (B,S,H*HD) bf16
#pragma unroll
  for (int r = 0; r < 4; r++) {
    float inv = 1.0f / l_i[r];
    int srow = q0 + w * 16 + quad * 4 + r;
#pragma unroll
    for (int ni = 0; ni < 8; ni++) {
      int col = ni * 16 + lr;
      out[(size_t)(b * SS + srow) * DD + h * HDD + col] =
          __float2bfloat16(oa[ni][r] * inv);
    }
  }
}

// ---------------- launch --------------------------------------------------
extern "C" void kernel_launch(void* const* d_in, const int* in_sizes, int n_in,
                              void* d_out, int out_size, void* d_ws, size_t ws_size,
                              hipStream_t stream) {
  (void)in_sizes; (void)n_in; (void)out_size; (void)ws_size;
  const float* x  = (const float*)d_in[0];
  const float* fc = (const float*)d_in[1];
  const float* fs = (const float*)d_in[2];
  const float* wq = (const float*)d_in[3];
  const float* wk = (const float*)d_in[4];
  const float* wv = (const float*)d_in[5];
  const float* wo = (const float*)d_in[6];

  char* ws = (char*)d_ws;
  bf16* xb   = (bf16*)(ws);                           // 32 MB  x bf16 (4096x4096)
  bf16* W    = (bf16*)(ws + (size_t)33554432);        // 32 MB  current weight bf16
  bf16* qb   = (bf16*)(ws + (size_t)67108864);        // 32 MB  q (B,S,H,HD)
  bf16* kb   = (bf16*)(ws + (size_t)100663296);       // 8 MB   k (B,S,KV,HD)
  bf16* vtb  = (bf16*)(ws + (size_t)109051904);       // 8 MB   v^T (B,KV,HD,S)
  bf16* attn = xb;                                    // reuse: x dead after V proj

  const int NX  = BB * SS * DD;   // 16777216
  const int NW  = DD * DD;        // 16777216
  const int NWK = KVH * HDD * DD; // 4194304

  cast_kernel<<<NX / 1024, 256, 0, stream>>>(x, xb, NX / 4);
  cast_kernel<<<NW / 1024, 256, 0, stream>>>(wq, W, NW / 4);
  gemm_bt<0><<<dim3(32, 32), 256, 0, stream>>>(xb, W, qb, BB * SS, DD, DD);
  cast_kernel<<<NWK / 1024, 256, 0, stream>>>(wk, W, NWK / 4);
  gemm_bt<0><<<dim3(8, 32), 256, 0, stream>>>(xb, W, kb, BB * SS, KVH * HDD, DD);
  cast_kernel<<<NWK / 1024, 256, 0, stream>>>(wv, W, NWK / 4);
  gemm_bt<2><<<dim3(8, 32), 256, 0, stream>>>(xb, W, vtb, BB * SS, KVH * HDD, DD);
  rope_kernel<<<(BB * SS * (HH + KVH) * 64) / 256, 256, 0, stream>>>(qb, kb, fc, fs);
  flash_kernel<<<dim3(SS / 64, HH, BB), 256, 0, stream>>>(qb, kb, vtb, attn);
  cast_kernel<<<NW / 1024, 256, 0, stream>>>(wo, W, NW / 4);
  gemm_bt<1><<<dim3(32, 32), 256, 0, stream>>>(attn, W, (float*)d_out, BB * SS, DD, DD);
}

// Round 2
// 858.506 us; speedup vs baseline: 1.1168x; 1.1168x over previous
//
#include <hip/hip_runtime.h>
#include <hip/hip_bf16.h>

#define BB 2
#define SS 2048
#define DD 4096
#define HH 32
#define KVH 8
#define HDD 128

using bf16 = __hip_bfloat16;
typedef __attribute__((ext_vector_type(8))) __bf16 bf16x8;
typedef __attribute__((ext_vector_type(4))) float f32x4;

#define GLOAD16(gp, lp) __builtin_amdgcn_global_load_lds(                     \
    (const __attribute__((address_space(1))) void*)(gp),                      \
    (__attribute__((address_space(3))) void*)(lp), 16, 0, 0)

// ---------------- fp32 -> bf16 cast (vectorized) ----------------
__global__ __launch_bounds__(256) void cast_kernel(
    const float* __restrict__ s, bf16* __restrict__ d, int n4) {
  int i = blockIdx.x * blockDim.x + threadIdx.x;
  if (i >= n4) return;
  float4 v = ((const float4*)s)[i];
  bf16 a0 = __float2bfloat16(v.x), a1 = __float2bfloat16(v.y);
  bf16 a2 = __float2bfloat16(v.z), a3 = __float2bfloat16(v.w);
  ushort4 u;
  u.x = reinterpret_cast<unsigned short&>(a0);
  u.y = reinterpret_cast<unsigned short&>(a1);
  u.z = reinterpret_cast<unsigned short&>(a2);
  u.w = reinterpret_cast<unsigned short&>(a3);
  ((ushort4*)d)[i] = u;
}

// ---------------- RoPE in place on q (B,S,H,HD) and k (B,S,KV,HD) ----------
__global__ __launch_bounds__(256) void rope_kernel(
    bf16* __restrict__ qb, bf16* __restrict__ kb,
    const float* __restrict__ fc, const float* __restrict__ fs) {
  int idx = blockIdx.x * blockDim.x + threadIdx.x;
  const int QP = BB * SS * HH * (HDD / 2);   // 8388608 q pairs
  const int KP = BB * SS * KVH * (HDD / 2);  // 2097152 k pairs
  bf16* p;
  int s, i;
  if (idx < QP) {
    int hr = idx >> 6;                 // (b*S+s)*H + h
    s = (hr >> 5) & (SS - 1);
    i = idx & 63;
    p = qb + ((size_t)hr << 7) + (i << 1);
  } else {
    int j = idx - QP;
    if (j >= KP) return;
    int hr = j >> 6;                   // (b*S+s)*KV + kv
    s = (hr >> 3) & (SS - 1);
    i = j & 63;
    p = kb + ((size_t)hr << 7) + (i << 1);
  }
  float c = fc[s * 64 + i], sn = fs[s * 64 + i];
  float x0 = __bfloat162float(p[0]), x1 = __bfloat162float(p[1]);
  p[0] = __float2bfloat16(x0 * c - x1 * sn);
  p[1] = __float2bfloat16(x0 * sn + x1 * c);
}

// ---------------- GEMM: C[M,N] = A[M,K] @ B[N,K]^T  (bf16 in, fp32 acc) ----
// MODE 0: bf16 row-major C; MODE 1: fp32 row-major C;
// MODE 2: bf16 store transposed-V layout vt[((b*KV+kv)*HD+d)*S + s]
template <int MODE>
__global__ __launch_bounds__(256, 2) void gemm_bt(
    const bf16* __restrict__ A, const bf16* __restrict__ Bm,
    void* __restrict__ C, int M, int N, int K) {
  __shared__ __attribute__((aligned(16))) bf16 As[128 * 64];  // 16 KB
  __shared__ __attribute__((aligned(16))) bf16 Bs[128 * 64];  // 16 KB
  const int m0 = blockIdx.y * 128, n0 = blockIdx.x * 128;
  const int t = threadIdx.x;
  const int lane = t & 63, w = t >> 6;
  const int wm = (w >> 1) * 64, wn = (w & 1) * 64;
  const int lr = lane & 15, quad = lane >> 4;

  // staging: tile rows 64B -> 8 chunks of 16B; XOR-swizzle chunk slot by row
  const int srow = t >> 3;                               // 0..31 (+32i)
  const int scol8 = ((t & 7) ^ (srow & 7)) * 8;          // i*32 doesn't change row&7
  const bf16* aSrc = A + (size_t)(m0 + srow) * K + scol8;
  const bf16* bSrc = Bm + (size_t)(n0 + srow) * K + scol8;
  bf16* aDst = As + t * 8;
  bf16* bDst = Bs + t * 8;

  // fragment read slots (swizzled), kk = 0/1
  const int sl[2] = {((0 * 4 + quad) ^ (lr & 7)) * 8, ((1 * 4 + quad) ^ (lr & 7)) * 8};

  f32x4 acc[4][4];
#pragma unroll
  for (int i = 0; i < 4; i++)
#pragma unroll
    for (int j = 0; j < 4; j++) acc[i][j] = (f32x4)0.0f;

  for (int k0 = 0; k0 < K; k0 += 64) {
#pragma unroll
    for (int i = 0; i < 4; i++) {
      GLOAD16(aSrc + i * 32 * K, aDst + i * 2048);
      GLOAD16(bSrc + i * 32 * K, bDst + i * 2048);
    }
    __syncthreads();
#pragma unroll
    for (int kk = 0; kk < 2; kk++) {
      bf16x8 af[4], bfv[4];
#pragma unroll
      for (int i = 0; i < 4; i++)
        af[i] = *(const bf16x8*)(As + (wm + i * 16 + lr) * 64 + sl[kk]);
#pragma unroll
      for (int j = 0; j < 4; j++)
        bfv[j] = *(const bf16x8*)(Bs + (wn + j * 16 + lr) * 64 + sl[kk]);
#pragma unroll
      for (int i = 0; i < 4; i++)
#pragma unroll
        for (int j = 0; j < 4; j++)
          acc[i][j] = __builtin_amdgcn_mfma_f32_16x16x32_bf16(af[i], bfv[j], acc[i][j], 0, 0, 0);
    }
    __syncthreads();
    aSrc += 64;
    bSrc += 64;
  }

  // epilogue: C/D layout col=lane&15, row=quad*4+reg
#pragma unroll
  for (int i = 0; i < 4; i++)
#pragma unroll
    for (int j = 0; j < 4; j++)
#pragma unroll
      for (int r = 0; r < 4; r++) {
        int row = m0 + wm + i * 16 + quad * 4 + r;
        int col = n0 + wn + j * 16 + lr;
        float v = acc[i][j][r];
        if (MODE == 0) {
          ((bf16*)C)[(size_t)row * N + col] = __float2bfloat16(v);
        } else if (MODE == 1) {
          ((float*)C)[(size_t)row * N + col] = v;
        } else {
          int bb = row >> 11, s = row & (SS - 1);
          int kv = col >> 7, d = col & (HDD - 1);
          ((bf16*)C)[((size_t)(bb * KVH + kv) * HDD + d) * SS + s] = __float2bfloat16(v);
        }
      }
}

// ---------------- causal flash attention, GQA (4 q-heads per kv-head) ------
// Q-tile 128 (4 waves x 32 rows), K-tile 64. Descending-qt schedule.
// q: (B,S,H,HD) bf16 (RoPE'd, pre-scaled here); k: (B,S,KV,HD) bf16;
// vt: (B,KV,HD,S) bf16 (pre-transposed); out: (B,S,H*HD) bf16
__global__ __launch_bounds__(256, 2) void flash_kernel(
    const bf16* __restrict__ q, const bf16* __restrict__ k,
    const bf16* __restrict__ vt, bf16* __restrict__ out) {
  __shared__ __attribute__((aligned(16))) bf16 Ks[64 * 128];  // 16 KB [key][d]
  __shared__ __attribute__((aligned(16))) bf16 Vs[128 * 64];  // 16 KB [d][key]
  __shared__ __attribute__((aligned(16))) bf16 Ps[128 * 72];  // 18 KB, stride 72
  const int qt = gridDim.x - 1 - blockIdx.x;  // longest blocks first
  const int h = blockIdx.y, b = blockIdx.z;
  const int kv = h >> 2;
  const int t = threadIdx.x;
  const int lane = t & 63, w = t >> 6;
  const int lr = lane & 15, quad = lane >> 4;
  const int q0 = qt * 128;
  const int wr = w * 32;  // wave's row base within the q-tile

  // Q fragments (A-layout): rows wr+mf*16+lr, k-chunks c*32+quad*8; pre-scaled
  bf16x8 qf[2][4];
#pragma unroll
  for (int mf = 0; mf < 2; mf++) {
    const bf16* qp =
        q + ((size_t)(b * SS + q0 + wr + mf * 16 + lr) * HH + h) * HDD + quad * 8;
#pragma unroll
    for (int c = 0; c < 4; c++) qf[mf][c] = *(const bf16x8*)(qp + c * 32);
  }
  const float scale = 0.08838834764831845f;  // 1/sqrt(128)
#pragma unroll
  for (int mf = 0; mf < 2; mf++)
#pragma unroll
    for (int c = 0; c < 4; c++)
#pragma unroll
      for (int j = 0; j < 8; j++)
        qf[mf][c][j] = (__bf16)((float)qf[mf][c][j] * scale);

  f32x4 oa[2][8];
#pragma unroll
  for (int mf = 0; mf < 2; mf++)
#pragma unroll
    for (int i = 0; i < 8; i++) oa[mf][i] = (f32x4)0.0f;
  float m_i[8], l_i[8];
#pragma unroll
  for (int r = 0; r < 8; r++) { m_i[r] = -1e30f; l_i[r] = 0.f; }

  // staging bases (XOR-swizzled source chunks; dest is forced lane-sequential)
  const int krow = t >> 4;                              // 0..15 (+16i)
  const int kcol8 = ((t & 15) ^ (krow & 15)) * 8;
  const bf16* kSrc0 = k + ((size_t)(b * SS + krow) * KVH + kv) * HDD + kcol8;
  const int vrow = t >> 3;                              // 0..31 (+32i)
  const int vcol8 = ((t & 7) ^ (vrow & 7)) * 8;
  const bf16* vSrc0 = vt + ((size_t)(b * KVH + kv) * HDD + vrow) * SS + vcol8;
  bf16* kDst = Ks + t * 8;
  bf16* vDst = Vs + t * 8;

  const int slV[2] = {((0 * 4 + quad) ^ (lr & 7)) * 8, ((1 * 4 + quad) ^ (lr & 7)) * 8};

  const int nkt = 2 * qt + 2;
  for (int kt = 0; kt < nkt; kt++) {
    const int kt0 = kt * 64;
    const bf16* kSrc = kSrc0 + (size_t)kt0 * (KVH * HDD);
    const bf16* vSrc = vSrc0 + kt0;
#pragma unroll
    for (int i = 0; i < 4; i++) {
      GLOAD16(kSrc + i * 16 * KVH * HDD, kDst + i * 2048);
      GLOAD16(vSrc + i * 32 * SS, vDst + i * 2048);
    }
    __syncthreads();

    // S = Q K^T : 2 m-frags x 4 n-frags, K-fragments shared across m
    f32x4 sc[2][4];
#pragma unroll
    for (int mf = 0; mf < 2; mf++)
#pragma unroll
      for (int ni = 0; ni < 4; ni++) sc[mf][ni] = (f32x4)0.0f;
#pragma unroll
    for (int c = 0; c < 4; c++) {
      bf16x8 kf[4];
#pragma unroll
      for (int ni = 0; ni < 4; ni++)
        kf[ni] = *(const bf16x8*)(Ks + (ni * 16 + lr) * 128 + (((c * 4 + quad) ^ lr) * 8));
#pragma unroll
      for (int mf = 0; mf < 2; mf++)
#pragma unroll
        for (int ni = 0; ni < 4; ni++)
          sc[mf][ni] = __builtin_amdgcn_mfma_f32_16x16x32_bf16(qf[mf][c], kf[ni], sc[mf][ni], 0, 0, 0);
    }

    // causal mask only on diagonal-straddling tiles (wave-uniform test)
    if (kt0 + 63 > q0 + wr) {
#pragma unroll
      for (int mf = 0; mf < 2; mf++)
#pragma unroll
        for (int ni = 0; ni < 4; ni++)
#pragma unroll
          for (int r = 0; r < 4; r++) {
            int kidx = kt0 + ni * 16 + lr;
            int qidx = q0 + wr + mf * 16 + quad * 4 + r;
            if (kidx > qidx) sc[mf][ni][r] = -1e30f;
          }
    }

    float mx[8];
#pragma unroll
    for (int r = 0; r < 8; r++) mx[r] = -1e30f;
#pragma unroll
    for (int mf = 0; mf < 2; mf++)
#pragma unroll
      for (int ni = 0; ni < 4; ni++)
#pragma unroll
        for (int r = 0; r < 4; r++)
          mx[mf * 4 + r] = fmaxf(mx[mf * 4 + r], sc[mf][ni][r]);
#pragma unroll
    for (int off = 1; off < 16; off <<= 1)
#pragma unroll
      for (int r = 0; r < 8; r++) mx[r] = fmaxf(mx[r], __shfl_xor(mx[r], off));

    float alpha[8], rs[8];
#pragma unroll
    for (int r = 0; r < 8; r++) {
      float mn = fmaxf(m_i[r], mx[r]);
      alpha[r] = __expf(m_i[r] - mn);
      m_i[r] = mn;
      rs[r] = 0.f;
    }
#pragma unroll
    for (int mf = 0; mf < 2; mf++)
#pragma unroll
      for (int ni = 0; ni < 4; ni++)
#pragma unroll
        for (int r = 0; r < 4; r++) {
          float p = __expf(sc[mf][ni][r] - m_i[mf * 4 + r]);
          sc[mf][ni][r] = p;
          rs[mf * 4 + r] += p;
        }
#pragma unroll
    for (int off = 1; off < 16; off <<= 1)
#pragma unroll
      for (int r = 0; r < 8; r++) rs[r] += __shfl_xor(rs[r], off);
#pragma unroll
    for (int r = 0; r < 8; r++) l_i[r] = l_i[r] * alpha[r] + rs[r];
#pragma unroll
    for (int mf = 0; mf < 2; mf++)
#pragma unroll
      for (int ni = 0; ni < 8; ni++)
#pragma unroll
        for (int r = 0; r < 4; r++) oa[mf][ni][r] *= alpha[mf * 4 + r];

    // P: C-layout -> LDS strip (wave-private rows, stride 72 = 16B-aligned)
#pragma unroll
    for (int mf = 0; mf < 2; mf++)
#pragma unroll
      for (int ni = 0; ni < 4; ni++)
#pragma unroll
        for (int r = 0; r < 4; r++)
          Ps[(wr + mf * 16 + quad * 4 + r) * 72 + ni * 16 + lr] =
              __float2bfloat16(sc[mf][ni][r]);

    // O += P @ V : V-fragments shared across the 2 m-frags
#pragma unroll
    for (int kk = 0; kk < 2; kk++) {
      bf16x8 pf[2];
#pragma unroll
      for (int mf = 0; mf < 2; mf++)
        pf[mf] = *(const bf16x8*)(Ps + (wr + mf * 16 + lr) * 72 + kk * 32 + quad * 8);
#pragma unroll
      for (int ni = 0; ni < 8; ni++) {
        bf16x8 vf = *(const bf16x8*)(Vs + (ni * 16 + lr) * 64 + slV[kk]);
#pragma unroll
        for (int mf = 0; mf < 2; mf++)
          oa[mf][ni] = __builtin_amdgcn_mfma_f32_16x16x32_bf16(pf[mf], vf, oa[mf][ni], 0, 0, 0);
      }
    }
    __syncthreads();
  }

  // epilogue: O / l, write (B,S,H*HD) bf16
#pragma unroll
  for (int mf = 0; mf < 2; mf++)
#pragma unroll
    for (int r = 0; r < 4; r++) {
      float inv = 1.0f / l_i[mf * 4 + r];
      int srow = q0 + wr + mf * 16 + quad * 4 + r;
#pragma unroll
      for (int ni = 0; ni < 8; ni++) {
        int col = ni * 16 + lr;
        out[(size_t)(b * SS + srow) * DD + h * HDD + col] =
            __float2bfloat16(oa[mf][ni][r] * inv);
      }
    }
}

// ---------------- launch --------------------------------------------------
extern "C" void kernel_launch(void* const* d_in, const int* in_sizes, int n_in,
                              void* d_out, int out_size, void* d_ws, size_t ws_size,
                              hipStream_t stream) {
  (void)in_sizes; (void)n_in; (void)out_size; (void)ws_size;
  const float* x  = (const float*)d_in[0];
  const float* fc = (const float*)d_in[1];
  const float* fs = (const float*)d_in[2];
  const float* wq = (const float*)d_in[3];
  const float* wk = (const float*)d_in[4];
  const float* wv = (const float*)d_in[5];
  const float* wo = (const float*)d_in[6];

  char* ws = (char*)d_ws;
  bf16* xb   = (bf16*)(ws);                           // 32 MB  x bf16 (4096x4096)
  bf16* W    = (bf16*)(ws + (size_t)33554432);        // 32 MB  current weight bf16
  bf16* qb   = (bf16*)(ws + (size_t)67108864);        // 32 MB  q (B,S,H,HD)
  bf16* kb   = (bf16*)(ws + (size_t)100663296);       // 8 MB   k (B,S,KV,HD)
  bf16* vtb  = (bf16*)(ws + (size_t)109051904);       // 8 MB   v^T (B,KV,HD,S)
  bf16* attn = xb;                                    // reuse: x dead after V proj

  const int NX  = BB * SS * DD;   // 16777216
  const int NW  = DD * DD;        // 16777216
  const int NWK = KVH * HDD * DD; // 4194304

  cast_kernel<<<NX / 1024, 256, 0, stream>>>(x, xb, NX / 4);
  cast_kernel<<<NW / 1024, 256, 0, stream>>>(wq, W, NW / 4);
  gemm_bt<0><<<dim3(32, 32), 256, 0, stream>>>(xb, W, qb, BB * SS, DD, DD);
  cast_kernel<<<NWK / 1024, 256, 0, stream>>>(wk, W, NWK / 4);
  gemm_bt<0><<<dim3(8, 32), 256, 0, stream>>>(xb, W, kb, BB * SS, KVH * HDD, DD);
  cast_kernel<<<NWK / 1024, 256, 0, stream>>>(wv, W, NWK / 4);
  gemm_bt<2><<<dim3(8, 32), 256, 0, stream>>>(xb, W, vtb, BB * SS, KVH * HDD, DD);
  rope_kernel<<<(BB * SS * (HH + KVH) * 64) / 256, 256, 0, stream>>>(qb, kb, fc, fs);
  flash_kernel<<<dim3(SS / 128, HH, BB), 256, 0, stream>>>(qb, kb, vtb, attn);
  cast_kernel<<<NW / 1024, 256, 0, stream>>>(wo, W, NW / 4);
  gemm_bt<1><<<dim3(32, 32), 256, 0, stream>>>(attn, W, (float*)d_out, BB * SS, DD, DD);
}

// Round 3
// 795.240 us; speedup vs baseline: 1.2056x; 1.0796x over previous
//
#include <hip/hip_runtime.h>
#include <hip/hip_bf16.h>

#define BB 2
#define SS 2048
#define DD 4096
#define HH 32
#define KVH 8
#define HDD 128

using bf16 = __hip_bfloat16;
typedef __attribute__((ext_vector_type(8))) __bf16 bf16x8;
typedef __attribute__((ext_vector_type(4))) float f32x4;

#define GLOAD16(gp, lp) __builtin_amdgcn_global_load_lds(                     \
    (const __attribute__((address_space(1))) void*)(gp),                      \
    (__attribute__((address_space(3))) void*)(lp), 16, 0, 0)

__device__ inline unsigned pack_bf16_2(float a, float b) {
  unsigned short ua = __bfloat16_as_ushort(__float2bfloat16(a));
  unsigned short ub = __bfloat16_as_ushort(__float2bfloat16(b));
  return (unsigned)ua | ((unsigned)ub << 16);
}

// ---------------- fp32 -> bf16 cast (vectorized) ----------------
__global__ __launch_bounds__(256) void cast_kernel(
    const float* __restrict__ s, bf16* __restrict__ d, int n4) {
  int i = blockIdx.x * blockDim.x + threadIdx.x;
  if (i >= n4) return;
  float4 v = ((const float4*)s)[i];
  bf16 a0 = __float2bfloat16(v.x), a1 = __float2bfloat16(v.y);
  bf16 a2 = __float2bfloat16(v.z), a3 = __float2bfloat16(v.w);
  ushort4 u;
  u.x = reinterpret_cast<unsigned short&>(a0);
  u.y = reinterpret_cast<unsigned short&>(a1);
  u.z = reinterpret_cast<unsigned short&>(a2);
  u.w = reinterpret_cast<unsigned short&>(a3);
  ((ushort4*)d)[i] = u;
}

// ---------------- RoPE in place; q additionally scaled by 1/sqrt(HD)*log2e -
__global__ __launch_bounds__(256) void rope_kernel(
    bf16* __restrict__ qb, bf16* __restrict__ kb,
    const float* __restrict__ fc, const float* __restrict__ fs) {
  const float QS = 0.08838834764831845f * 1.4426950408889634f;
  int idx = blockIdx.x * blockDim.x + threadIdx.x;
  const int QP = BB * SS * HH * (HDD / 2);   // 8388608 q pairs
  const int KP = BB * SS * KVH * (HDD / 2);  // 2097152 k pairs
  bf16* p;
  int s, i;
  float g;
  if (idx < QP) {
    int hr = idx >> 6;                 // (b*S+s)*H + h
    s = (hr >> 5) & (SS - 1);
    i = idx & 63;
    p = qb + ((size_t)hr << 7) + (i << 1);
    g = QS;
  } else {
    int j = idx - QP;
    if (j >= KP) return;
    int hr = j >> 6;                   // (b*S+s)*KV + kv
    s = (hr >> 3) & (SS - 1);
    i = j & 63;
    p = kb + ((size_t)hr << 7) + (i << 1);
    g = 1.0f;
  }
  float c = fc[s * 64 + i], sn = fs[s * 64 + i];
  float x0 = __bfloat162float(p[0]), x1 = __bfloat162float(p[1]);
  p[0] = __float2bfloat16((x0 * c - x1 * sn) * g);
  p[1] = __float2bfloat16((x0 * sn + x1 * c) * g);
}

// ---------------- GEMM: C[M,N] = A[M,K] @ B[N,K]^T  (bf16 in, fp32 acc) ----
// MODE 0: bf16 row-major C; MODE 1: fp32 row-major C;
// MODE 2: KV fused (N=2048): col<1024 -> k row-major; col>=1024 -> v
//         transposed layout C2[((b*KV+kv)*HD+d)*S + s]
template <int MODE>
__global__ __launch_bounds__(256, 2) void gemm_bt(
    const bf16* __restrict__ A, const bf16* __restrict__ Bm,
    void* __restrict__ C, void* __restrict__ C2, int M, int N, int K) {
  __shared__ __attribute__((aligned(16))) bf16 As[128 * 64];  // 16 KB
  __shared__ __attribute__((aligned(16))) bf16 Bs[128 * 64];  // 16 KB
  const int m0 = blockIdx.y * 128, n0 = blockIdx.x * 128;
  const int t = threadIdx.x;
  const int lane = t & 63, w = t >> 6;
  const int wm = (w >> 1) * 64, wn = (w & 1) * 64;
  const int lr = lane & 15, quad = lane >> 4;

  // staging: tile rows 64B -> 8 chunks of 16B; XOR-swizzle chunk slot by row
  const int srow = t >> 3;                               // 0..31 (+32i)
  const int scol8 = ((t & 7) ^ (srow & 7)) * 8;          // i*32 doesn't change row&7
  const bf16* aSrc = A + (size_t)(m0 + srow) * K + scol8;
  const bf16* bSrc = Bm + (size_t)(n0 + srow) * K + scol8;
  bf16* aDst = As + t * 8;
  bf16* bDst = Bs + t * 8;

  // fragment read slots (swizzled), kk = 0/1
  const int sl[2] = {((0 * 4 + quad) ^ (lr & 7)) * 8, ((1 * 4 + quad) ^ (lr & 7)) * 8};

  f32x4 acc[4][4];
#pragma unroll
  for (int i = 0; i < 4; i++)
#pragma unroll
    for (int j = 0; j < 4; j++) acc[i][j] = (f32x4)0.0f;

  for (int k0 = 0; k0 < K; k0 += 64) {
#pragma unroll
    for (int i = 0; i < 4; i++) {
      GLOAD16(aSrc + i * 32 * K, aDst + i * 2048);
      GLOAD16(bSrc + i * 32 * K, bDst + i * 2048);
    }
    __syncthreads();
#pragma unroll
    for (int kk = 0; kk < 2; kk++) {
      bf16x8 af[4], bfv[4];
#pragma unroll
      for (int i = 0; i < 4; i++)
        af[i] = *(const bf16x8*)(As + (wm + i * 16 + lr) * 64 + sl[kk]);
#pragma unroll
      for (int j = 0; j < 4; j++)
        bfv[j] = *(const bf16x8*)(Bs + (wn + j * 16 + lr) * 64 + sl[kk]);
#pragma unroll
      for (int i = 0; i < 4; i++)
#pragma unroll
        for (int j = 0; j < 4; j++)
          acc[i][j] = __builtin_amdgcn_mfma_f32_16x16x32_bf16(af[i], bfv[j], acc[i][j], 0, 0, 0);
    }
    __syncthreads();
    aSrc += 64;
    bSrc += 64;
  }

  // epilogue: C/D layout col=lane&15, row=quad*4+reg
#pragma unroll
  for (int i = 0; i < 4; i++)
#pragma unroll
    for (int j = 0; j < 4; j++)
#pragma unroll
      for (int r = 0; r < 4; r++) {
        int row = m0 + wm + i * 16 + quad * 4 + r;
        int col = n0 + wn + j * 16 + lr;
        float v = acc[i][j][r];
        if (MODE == 0) {
          ((bf16*)C)[(size_t)row * N + col] = __float2bfloat16(v);
        } else if (MODE == 1) {
          ((float*)C)[(size_t)row * N + col] = v;
        } else {
          if (n0 < 1024) {
            ((bf16*)C)[(size_t)row * 1024 + col] = __float2bfloat16(v);
          } else {
            int c2 = col - 1024;
            int kv = c2 >> 7, d = c2 & (HDD - 1);
            int bb = row >> 11, s = row & (SS - 1);
            ((bf16*)C2)[((size_t)(bb * KVH + kv) * HDD + d) * SS + s] =
                __float2bfloat16(v);
          }
        }
      }
}

// ---------------- causal flash attention, GQA (4 q-heads per kv-head) ------
// Computes S^T (query on MFMA column axis -> cheap column reductions and
// vectorized P stores). Q pre-scaled by 1/sqrt(HD)*log2e in rope; softmax
// in exp2 domain. Q-tile 128 (4 waves x 32 rows), K-tile 64.
__global__ __launch_bounds__(256, 2) void flash_kernel(
    const bf16* __restrict__ q, const bf16* __restrict__ k,
    const bf16* __restrict__ vt, bf16* __restrict__ out) {
  __shared__ __attribute__((aligned(16))) bf16 Ks[64 * 128];  // 16 KB [key][d]
  __shared__ __attribute__((aligned(16))) bf16 Vs[128 * 64];  // 16 KB [d][key]
  __shared__ __attribute__((aligned(16))) bf16 Ps[128 * 72];  // 18 KB [q][key]
  const int qt = gridDim.x - 1 - blockIdx.x;  // longest blocks first
  const int h = blockIdx.y, b = blockIdx.z;
  const int kv = h >> 2;
  const int t = threadIdx.x;
  const int lane = t & 63, w = t >> 6;
  const int lr = lane & 15, quad = lane >> 4;
  const int q0 = qt * 128;
  const int wr = w * 32;  // wave's row base within the q-tile

  // Q fragments (used as MFMA B operand): rows wr+mf*16+lr, k-chunks c*32+quad*8
  bf16x8 qf[2][4];
#pragma unroll
  for (int mf = 0; mf < 2; mf++) {
    const bf16* qp =
        q + ((size_t)(b * SS + q0 + wr + mf * 16 + lr) * HH + h) * HDD + quad * 8;
#pragma unroll
    for (int c = 0; c < 4; c++) qf[mf][c] = *(const bf16x8*)(qp + c * 32);
  }

  f32x4 oa[2][8];
#pragma unroll
  for (int mf = 0; mf < 2; mf++)
#pragma unroll
    for (int i = 0; i < 8; i++) oa[mf][i] = (f32x4)0.0f;
  // softmax state for query (wr + mf*16 + lr), log2 domain
  float m_i[2] = {-1e30f, -1e30f}, l_i[2] = {0.f, 0.f};

  // staging bases (XOR-swizzled source chunks; dest is forced lane-sequential)
  const int krow = t >> 4;                              // 0..15 (+16i)
  const int kcol8 = ((t & 15) ^ (krow & 15)) * 8;
  const bf16* kSrc0 = k + ((size_t)(b * SS + krow) * KVH + kv) * HDD + kcol8;
  const int vrow = t >> 3;                              // 0..31 (+32i)
  const int vcol8 = ((t & 7) ^ (vrow & 7)) * 8;
  const bf16* vSrc0 = vt + ((size_t)(b * KVH + kv) * HDD + vrow) * SS + vcol8;
  bf16* kDst = Ks + t * 8;
  bf16* vDst = Vs + t * 8;

  const int slV[2] = {((0 * 4 + quad) ^ (lr & 7)) * 8, ((1 * 4 + quad) ^ (lr & 7)) * 8};
  // wave-private P strips
  bf16* psw0 = Ps + (wr + lr) * 72;
  bf16* psw1 = Ps + (wr + 16 + lr) * 72;

  const int nkt = 2 * qt + 2;
  for (int kt = 0; kt < nkt; kt++) {
    const int kt0 = kt * 64;
    const bf16* kSrc = kSrc0 + (size_t)kt0 * (KVH * HDD);
    const bf16* vSrc = vSrc0 + kt0;
#pragma unroll
    for (int i = 0; i < 4; i++) {
      GLOAD16(kSrc + i * 16 * KVH * HDD, kDst + i * 2048);
      GLOAD16(vSrc + i * 32 * SS, vDst + i * 2048);
    }
    __syncthreads();

    // S^T = K Q^T : st[mf][ni] has col=lane&15=query(in block mf),
    // row=quad*4+r = key (ni*16+quad*4+r)
    f32x4 st[2][4];
#pragma unroll
    for (int mf = 0; mf < 2; mf++)
#pragma unroll
      for (int ni = 0; ni < 4; ni++) st[mf][ni] = (f32x4)0.0f;
#pragma unroll
    for (int c = 0; c < 4; c++) {
      bf16x8 kf[4];
#pragma unroll
      for (int ni = 0; ni < 4; ni++)
        kf[ni] = *(const bf16x8*)(Ks + (ni * 16 + lr) * 128 + (((c * 4 + quad) ^ lr) * 8));
#pragma unroll
      for (int mf = 0; mf < 2; mf++)
#pragma unroll
        for (int ni = 0; ni < 4; ni++)
          st[mf][ni] = __builtin_amdgcn_mfma_f32_16x16x32_bf16(kf[ni], qf[mf][c], st[mf][ni], 0, 0, 0);
    }

    // causal mask only on diagonal-straddling tiles (wave-uniform test)
    if (kt0 + 63 > q0 + wr) {
#pragma unroll
      for (int mf = 0; mf < 2; mf++) {
        int qidx = q0 + wr + mf * 16 + lr;
#pragma unroll
        for (int ni = 0; ni < 4; ni++)
#pragma unroll
          for (int r = 0; r < 4; r++) {
            int kidx = kt0 + ni * 16 + quad * 4 + r;
            if (kidx > qidx) st[mf][ni][r] = -1e30f;
          }
      }
    }

    // online softmax per query column (2 shuffles per reduction)
    float alpha[2], rs[2];
#pragma unroll
    for (int mf = 0; mf < 2; mf++) {
      float mx = st[mf][0][0];
#pragma unroll
      for (int ni = 0; ni < 4; ni++)
#pragma unroll
        for (int r = 0; r < 4; r++) mx = fmaxf(mx, st[mf][ni][r]);
      mx = fmaxf(mx, __shfl_xor(mx, 16));
      mx = fmaxf(mx, __shfl_xor(mx, 32));
      float mn = fmaxf(m_i[mf], mx);
      alpha[mf] = __builtin_amdgcn_exp2f(m_i[mf] - mn);
      m_i[mf] = mn;
      float s = 0.f;
#pragma unroll
      for (int ni = 0; ni < 4; ni++)
#pragma unroll
        for (int r = 0; r < 4; r++) {
          float p = __builtin_amdgcn_exp2f(st[mf][ni][r] - mn);
          st[mf][ni][r] = p;
          s += p;
        }
      s += __shfl_xor(s, 16);
      s += __shfl_xor(s, 32);
      rs[mf] = s;
      l_i[mf] = l_i[mf] * alpha[mf] + s;
    }

    // P store: 4 contiguous keys per lane -> ds_write_b64
#pragma unroll
    for (int ni = 0; ni < 4; ni++) {
      uint2 u0, u1;
      u0.x = pack_bf16_2(st[0][ni][0], st[0][ni][1]);
      u0.y = pack_bf16_2(st[0][ni][2], st[0][ni][3]);
      u1.x = pack_bf16_2(st[1][ni][0], st[1][ni][1]);
      u1.y = pack_bf16_2(st[1][ni][2], st[1][ni][3]);
      *(uint2*)(psw0 + ni * 16 + quad * 4) = u0;
      *(uint2*)(psw1 + ni * 16 + quad * 4) = u1;
    }

    // broadcast alpha into O-accumulator view (query = quad*4+r) and rescale
#pragma unroll
    for (int mf = 0; mf < 2; mf++) {
      f32x4 av;
#pragma unroll
      for (int r = 0; r < 4; r++) av[r] = __shfl(alpha[mf], quad * 4 + r);
#pragma unroll
      for (int ni = 0; ni < 8; ni++) oa[mf][ni] *= av;
    }

    // O += P @ V : A = P (b128 from own strip), B = V^T rows
#pragma unroll
    for (int kk = 0; kk < 2; kk++) {
      bf16x8 pf[2];
      pf[0] = *(const bf16x8*)(psw0 + kk * 32 + quad * 8);
      pf[1] = *(const bf16x8*)(psw1 + kk * 32 + quad * 8);
#pragma unroll
      for (int ni = 0; ni < 8; ni++) {
        bf16x8 vf = *(const bf16x8*)(Vs + (ni * 16 + lr) * 64 + slV[kk]);
#pragma unroll
        for (int mf = 0; mf < 2; mf++)
          oa[mf][ni] = __builtin_amdgcn_mfma_f32_16x16x32_bf16(pf[mf], vf, oa[mf][ni], 0, 0, 0);
      }
    }
    __syncthreads();
  }

  // epilogue: O / l (broadcast into oa view), write (B,S,H*HD) bf16
#pragma unroll
  for (int mf = 0; mf < 2; mf++) {
    f32x4 linv;
#pragma unroll
    for (int r = 0; r < 4; r++) linv[r] = 1.0f / __shfl(l_i[mf], quad * 4 + r);
#pragma unroll
    for (int r = 0; r < 4; r++) {
      int srow = q0 + wr + mf * 16 + quad * 4 + r;
#pragma unroll
      for (int ni = 0; ni < 8; ni++) {
        int col = ni * 16 + lr;
        out[(size_t)(b * SS + srow) * DD + h * HDD + col] =
            __float2bfloat16(oa[mf][ni][r] * linv[r]);
      }
    }
  }
}

// ---------------- launch --------------------------------------------------
extern "C" void kernel_launch(void* const* d_in, const int* in_sizes, int n_in,
                              void* d_out, int out_size, void* d_ws, size_t ws_size,
                              hipStream_t stream) {
  (void)in_sizes; (void)n_in; (void)out_size; (void)ws_size;
  const float* x  = (const float*)d_in[0];
  const float* fc = (const float*)d_in[1];
  const float* fs = (const float*)d_in[2];
  const float* wq = (const float*)d_in[3];
  const float* wk = (const float*)d_in[4];
  const float* wv = (const float*)d_in[5];
  const float* wo = (const float*)d_in[6];

  char* ws = (char*)d_ws;
  bf16* xb   = (bf16*)(ws);                           // 32 MB  x bf16 (4096x4096)
  bf16* W    = (bf16*)(ws + (size_t)33554432);        // 32 MB  current weight bf16
  bf16* qb   = (bf16*)(ws + (size_t)67108864);        // 32 MB  q (B,S,H,HD)
  bf16* kb   = (bf16*)(ws + (size_t)100663296);       // 8 MB   k (B,S,KV,HD)
  bf16* vtb  = (bf16*)(ws + (size_t)109051904);       // 8 MB   v^T (B,KV,HD,S)
  bf16* attn = xb;                                    // reuse: x dead after KV proj

  const int NX  = BB * SS * DD;   // 16777216
  const int NW  = DD * DD;        // 16777216
  const int NWK = KVH * HDD * DD; // 4194304

  cast_kernel<<<NX / 1024, 256, 0, stream>>>(x, xb, NX / 4);
  cast_kernel<<<NW / 1024, 256, 0, stream>>>(wq, W, NW / 4);
  gemm_bt<0><<<dim3(32, 32), 256, 0, stream>>>(xb, W, qb, nullptr, BB * SS, DD, DD);
  cast_kernel<<<NWK / 1024, 256, 0, stream>>>(wk, W, NWK / 4);
  cast_kernel<<<NWK / 1024, 256, 0, stream>>>(wv, W + 4194304, NWK / 4);
  gemm_bt<2><<<dim3(16, 32), 256, 0, stream>>>(xb, W, kb, vtb, BB * SS, 2048, DD);
  rope_kernel<<<(BB * SS * (HH + KVH) * 64) / 256, 256, 0, stream>>>(qb, kb, fc, fs);
  flash_kernel<<<dim3(SS / 128, HH, BB), 256, 0, stream>>>(qb, kb, vtb, attn);
  cast_kernel<<<NW / 1024, 256, 0, stream>>>(wo, W, NW / 4);
  gemm_bt<1><<<dim3(32, 32), 256, 0, stream>>>(attn, W, (float*)d_out, nullptr, BB * SS, DD, DD);
}